// Round 6
// baseline (161.358 us; speedup 1.0000x reference)
//
#include <hip/hip_runtime.h>
#include <math.h>

#define KDIM 512
#define NDIM 4096
#define MEMD 64
#define WTAPS 16
#define SEG 1024
#define NSEG (NDIM / SEG)          // 4
#define NPART (KDIM * NSEG)        // 2048 partials

#define GBM 64
#define GBN 64
#define GBK 64

typedef short bf16x8 __attribute__((ext_vector_type(8)));
typedef float f32x4 __attribute__((ext_vector_type(4)));

#define GLOAD_LDS16(g, l) __builtin_amdgcn_global_load_lds( \
    (const __attribute__((address_space(1))) unsigned int*)(g), \
    (__attribute__((address_space(3))) unsigned int*)(l), 16, 0, 0)

// ---- bf16 hi/lo split (RTNE) ----
__device__ __forceinline__ void bsplit(float a, ushort& hi, ushort& lo) {
    uint u = __float_as_uint(a);
    uint h = (u + 0x7FFFu + ((u >> 16) & 1u)) >> 16;
    hi = (ushort)h;
    float hf = __uint_as_float(h << 16);
    float r = a - hf;                       // exact (Sterbenz)
    uint u2 = __float_as_uint(r);
    lo = (ushort)((u2 + 0x7FFFu + ((u2 >> 16) & 1u)) >> 16);
}

__device__ __forceinline__ float block_reduce_256(float v, float* sbuf) {
    #pragma unroll
    for (int off = 32; off > 0; off >>= 1) v += __shfl_down(v, off, 64);
    int lane = threadIdx.x & 63, wid = threadIdx.x >> 6;
    if (lane == 0) sbuf[wid] = v;
    __syncthreads();
    float tot = sbuf[0] + sbuf[1] + sbuf[2] + sbuf[3];
    __syncthreads();
    return tot;
}

__device__ __forceinline__ double block_reduce_256d(double v, double* dbuf) {
    #pragma unroll
    for (int off = 32; off > 0; off >>= 1) v += __shfl_down(v, off, 64);
    int lane = threadIdx.x & 63, wid = threadIdx.x >> 6;
    if (lane == 0) dbuf[wid] = v;
    __syncthreads();
    double tot = dbuf[0] + dbuf[1] + dbuf[2] + dbuf[3];
    __syncthreads();
    return tot;
}

// ---- fused conversion: B transpose+split [0,2048) | A split [2048,2176) | mu [2176,2688) ----
__global__ __launch_bounds__(256) void conv_kernel(
    const float* __restrict__ B, const float* __restrict__ A,
    ushort* __restrict__ Bthi, ushort* __restrict__ Btlo,
    ushort* __restrict__ Ahi, ushort* __restrict__ Alo,
    unsigned int* __restrict__ cnt, float* __restrict__ mu) {
    __shared__ float s[32][33];
    int b = blockIdx.x, tid = threadIdx.x;
    if (b < 2048) {
        int n0 = (b & 127) * 32, k0 = (b >> 7) * 32;
        int r = tid >> 5, c = tid & 31;
        #pragma unroll
        for (int i = 0; i < 4; ++i)
            s[r + i * 8][c] = B[(size_t)(k0 + r + i * 8) * NDIM + n0 + c];
        __syncthreads();
        int rr = tid >> 4, cc = (tid & 15) * 2;
        #pragma unroll
        for (int i = 0; i < 2; ++i) {
            int n = rr + i * 16;
            float a0 = s[cc][n], a1 = s[cc + 1][n];
            ushort h0, l0, h1, l1;
            bsplit(a0, h0, l0); bsplit(a1, h1, l1);
            size_t o = (size_t)(n0 + n) * KDIM + k0 + cc;
            *(ushort2*)&Bthi[o] = make_ushort2(h0, h1);
            *(ushort2*)&Btlo[o] = make_ushort2(l0, l1);
        }
    } else if (b < 2176) {
        int ab = b - 2048;
        if (ab == 0 && tid == 0) atomicExch(cnt, 0u);
        int g = ab * 256 + tid;
        const float4* src = (const float4*)A;
        #pragma unroll
        for (int i = 0; i < 2; ++i) {
            float4 v = src[g * 2 + i];
            ushort4 h, l;
            bsplit(v.x, h.x, l.x); bsplit(v.y, h.y, l.y);
            bsplit(v.z, h.z, l.z); bsplit(v.w, h.w, l.w);
            *(ushort4*)&Ahi[(size_t)g * 8 + i * 4] = h;
            *(ushort4*)&Alo[(size_t)g * 8 + i * 4] = l;
        }
    } else {                                   // mu rows (round-2 passing order)
        int k = b - 2176;
        const float* row = B + (size_t)k * NDIM;
        float ss = 0.f;
        for (int j = tid; j < NDIM; j += 256) ss += row[j];
        float tot = block_reduce_256(ss, &s[0][0]);
        if (tid == 0) mu[k] = tot / (float)NDIM / 10.0f + 0.01f;
    }
}

// ---- T = alpha @ obs via split-bf16 MFMA; global_load_lds staging (unchanged, known-good) ----
__global__ __launch_bounds__(256) void mfma_gemm(
    const ushort* __restrict__ Ahi, const ushort* __restrict__ Alo,
    const ushort* __restrict__ Bthi, const ushort* __restrict__ Btlo,
    float* __restrict__ C) {
    __shared__ __align__(16) ushort Asm[2][GBM * GBK];
    __shared__ __align__(16) ushort Bsm[2][GBN * GBK];
    int tid = threadIdx.x;
    int m0 = blockIdx.y * GBM, n0 = blockIdx.x * GBN;
    int l = tid & 63, w = tid >> 6;
    int wm = w >> 1, wn = w & 1;
    int lr = l & 15, lk = l >> 4;

    f32x4 acc[2][2];
    #pragma unroll
    for (int i = 0; i < 2; ++i)
        #pragma unroll
        for (int j = 0; j < 2; ++j) acc[i][j] = (f32x4){0.f, 0.f, 0.f, 0.f};

    for (int c0 = 0; c0 < KDIM; c0 += GBK) {
        #pragma unroll
        for (int i = 0; i < 4; ++i) {
            int c = tid + i * 256;                   // linear chunk id, lane-consecutive
            int plane = c >> 9, q = c & 511;
            int row = q >> 3, kc = (q & 7) ^ (row & 7);
            const ushort* sa = (plane ? Alo : Ahi) + (size_t)(m0 + row) * KDIM + c0 + kc * 8;
            GLOAD_LDS16(sa, (char*)&Asm[0][0] + c * 16);
            const ushort* sb = (plane ? Btlo : Bthi) + (size_t)(n0 + row) * KDIM + c0 + kc * 8;
            GLOAD_LDS16(sb, (char*)&Bsm[0][0] + c * 16);
        }
        __syncthreads();
        bf16x8 ah[2][2], al[2][2], bh[2][2], bl[2][2];   // [frag][k-slice]
        #pragma unroll
        for (int mf = 0; mf < 2; ++mf)
            #pragma unroll
            for (int s = 0; s < 2; ++s) {
                int ra = wm * 32 + mf * 16 + lr;
                int offa = ra * 128 + (((s * 64) + lk * 16) ^ ((ra & 7) << 4));
                ah[mf][s] = *(const bf16x8*)((const char*)&Asm[0][0] + offa);
                al[mf][s] = *(const bf16x8*)((const char*)&Asm[1][0] + offa);
                int rb = wn * 32 + mf * 16 + lr;
                int offb = rb * 128 + (((s * 64) + lk * 16) ^ ((rb & 7) << 4));
                bh[mf][s] = *(const bf16x8*)((const char*)&Bsm[0][0] + offb);
                bl[mf][s] = *(const bf16x8*)((const char*)&Bsm[1][0] + offb);
            }
        #pragma unroll
        for (int s = 0; s < 2; ++s)
            #pragma unroll
            for (int mf = 0; mf < 2; ++mf)
                #pragma unroll
                for (int nf = 0; nf < 2; ++nf) {
                    acc[mf][nf] = __builtin_amdgcn_mfma_f32_16x16x32_bf16(ah[mf][s], bh[nf][s], acc[mf][nf], 0, 0, 0);
                    acc[mf][nf] = __builtin_amdgcn_mfma_f32_16x16x32_bf16(ah[mf][s], bl[nf][s], acc[mf][nf], 0, 0, 0);
                    acc[mf][nf] = __builtin_amdgcn_mfma_f32_16x16x32_bf16(al[mf][s], bh[nf][s], acc[mf][nf], 0, 0, 0);
                }
        __syncthreads();
    }
    #pragma unroll
    for (int mf = 0; mf < 2; ++mf)
        #pragma unroll
        for (int nf = 0; nf < 2; ++nf)
            #pragma unroll
            for (int j = 0; j < 4; ++j) {
                int rm = m0 + wm * 32 + mf * 16 + lk * 4 + j;
                int cn = n0 + wn * 32 + nf * 16 + lr;
                C[(size_t)rm * NDIM + cn] = acc[mf][nf][j];
            }
}

// ---- segmented fused kernel: 2048 blocks = (k, seg); high occupancy, linear LDS ----
__global__ __launch_bounds__(256, 6) void final_kernel(
    const float* __restrict__ T, const float* __restrict__ obs,
    const float* __restrict__ extobs, const float* __restrict__ gamma,
    const float* __restrict__ beta_p, const float* __restrict__ mu,
    float* __restrict__ lams_out, double* __restrict__ partials,
    unsigned int* __restrict__ cnt, float* __restrict__ loglik_out) {
    __shared__ float Ts[SEG + 16];     // T[k, s*SEG-16 .. s*SEG+SEG)
    __shared__ float Es[SEG + 64];     // E[k, s*SEG-64 .. s*SEG+SEG)
    __shared__ float Os[SEG];
    __shared__ float Gs[MEMD];
    __shared__ float Wt[WTAPS];
    __shared__ double dbuf[4];
    __shared__ unsigned int flagS;

    int b = blockIdx.x, tid = threadIdx.x;
    int k = b >> 2, s = b & 3;
    float beta = *beta_p;
    float muk = mu[k];

    const float4* gT = (const float4*)(T + (size_t)k * NDIM);
    const float4* gE = (const float4*)(extobs + (size_t)k * NDIM);
    const float4* gO = (const float4*)(obs + (size_t)k * NDIM);
    float4 z = make_float4(0.f, 0.f, 0.f, 0.f);

    {   // Ts: 260 float4, global idx s*256-4+i (zero for t<0)
        #pragma unroll
        for (int i = tid; i < 260; i += 256) {
            int gi = s * 256 - 4 + i;
            ((float4*)Ts)[i] = (gi >= 0) ? gT[gi] : z;
        }
        // Es: 272 float4, global idx s*256-16+i (zero for t<0)
        #pragma unroll
        for (int i = tid; i < 272; i += 256) {
            int gi = s * 256 - 16 + i;
            ((float4*)Es)[i] = (gi >= 0) ? gE[gi] : z;
        }
        ((float4*)Os)[tid] = gO[s * 256 + tid];
        if (tid < MEMD) Gs[tid] = gamma[(size_t)k * MEMD + tid];
        if (tid >= 64 && tid < 64 + WTAPS) {
            int m = tid - 63;                  // 1..16
            Wt[m - 1] = beta * expf(-beta * (float)m);
        }
    }
    __syncthreads();

    int t_loc = tid * 4;                       // segment-local t
    int t = s * SEG + t_loc;                   // global t
    float win[20];
    float l1[4] = {0.f, 0.f, 0.f, 0.f};
    float l2[4] = {0.f, 0.f, 0.f, 0.f};

    // lam1: 16-tap decay FIR; T[t+j-m] = Ts[t_loc+16+j-m]
    #pragma unroll
    for (int c = 0; c < 5; ++c) *(float4*)&win[c * 4] = *(const float4*)&Ts[t_loc + c * 4];
    #pragma unroll
    for (int m = 1; m <= WTAPS; ++m) {
        float wm = Wt[m - 1];
        #pragma unroll
        for (int j = 0; j < 4; ++j) l1[j] = fmaf(wm, win[16 + j - m], l1[j]);
    }

    // lam2: 64 taps in 4 chunks of 16; E[(t+j)-64+i] = Es[t_loc + i + j]
    #pragma unroll
    for (int c4 = 0; c4 < 4; ++c4) {
        #pragma unroll
        for (int c = 0; c < 5; ++c)
            *(float4*)&win[c * 4] = *(const float4*)&Es[t_loc + c4 * 16 + c * 4];
        #pragma unroll
        for (int i = 0; i < 16; ++i) {
            float g = Gs[c4 * 16 + i];
            #pragma unroll
            for (int j = 0; j < 4; ++j) l2[j] = fmaf(g, win[i + j], l2[j]);
        }
    }
    if (t < MEMD) { l2[0] = 0.f; l2[1] = 0.f; l2[2] = 0.f; l2[3] = 0.f; }

    float4 o = ((const float4*)Os)[tid];
    float oo[4] = {o.x, o.y, o.z, o.w};
    double part = 0.0;
    f32x4 sv;
    #pragma unroll
    for (int j = 0; j < 4; ++j) {
        float x = muk + l1[j] + l2[j];
        float sp = fmaxf(x, 0.f) + log1pf(expf(-fabsf(x)));   // jax softplus
        sv[j] = sp;
        part += (double)(oo[j] * logf(sp) - sp);
    }
    *(f32x4*)&lams_out[(size_t)k * NDIM + t] = sv;

    double dtot = block_reduce_256d(part, dbuf);
    if (tid == 0) {
        partials[b] = dtot;
        __threadfence();
        unsigned int old = atomicAdd(cnt, 1u);
        flagS = (old == (unsigned int)(NPART - 1)) ? 1u : 0u;
    }
    __syncthreads();
    if (flagS) {                               // last block: deterministic f64 tree
        __threadfence();
        double v = 0.0;
        for (int j = tid; j < NPART; j += 256) v += partials[j];
        double tot = block_reduce_256d(v, dbuf);
        if (tid == 0) loglik_out[0] = (float)tot;
    }
}

extern "C" void kernel_launch(void* const* d_in, const int* in_sizes, int n_in,
                              void* d_out, int out_size, void* d_ws, size_t ws_size,
                              hipStream_t stream) {
    const float* obs    = (const float*)d_in[0];
    const float* extobs = (const float*)d_in[1];
    const float* beta   = (const float*)d_in[2];
    const float* alpha  = (const float*)d_in[3];
    const float* gamma  = (const float*)d_in[4];
    float* out = (float*)d_out;

    char* ws = (char*)d_ws;
    float*  T        = (float*)(ws);                              // 8 MiB
    ushort* Bthi     = (ushort*)(ws + (8u << 20));                // 4 MiB
    ushort* Btlo     = (ushort*)(ws + (12u << 20));               // 4 MiB
    ushort* Ahi      = (ushort*)(ws + (16u << 20));               // 0.5 MiB
    ushort* Alo      = (ushort*)(ws + (16u << 20) + (512u << 10));// 0.5 MiB
    double* partials = (double*)(ws + (17u << 20));               // 16 KiB
    unsigned int* cnt = (unsigned int*)(ws + (17u << 20) + (16u << 10));
    float* mu        = (float*)(ws + (17u << 20) + (16u << 10) + 256);

    conv_kernel<<<2048 + 128 + 512, 256, 0, stream>>>(obs, alpha, Bthi, Btlo,
                                                      Ahi, Alo, cnt, mu);
    mfma_gemm<<<dim3(NDIM / GBN, KDIM / GBM), 256, 0, stream>>>(Ahi, Alo, Bthi, Btlo, T);
    final_kernel<<<NPART, 256, 0, stream>>>(T, obs, extobs, gamma, beta, mu,
                                            out + 1, partials, cnt, out);
}

// Round 7
// 115.983 us; speedup vs baseline: 1.3912x; 1.3912x over previous
//
#include <hip/hip_runtime.h>
#include <math.h>

#define KDIM 512
#define NDIM 4096
#define MEMD 64
#define WTAPS 16
#define SEG 1024
#define NSEG (NDIM / SEG)          // 4
#define NPART (KDIM * NSEG)        // 2048 partials

#define GBM 64
#define GBN 64
#define GBK 64

typedef short bf16x8 __attribute__((ext_vector_type(8)));
typedef float f32x4 __attribute__((ext_vector_type(4)));

#define GLOAD_LDS16(g, l) __builtin_amdgcn_global_load_lds( \
    (const __attribute__((address_space(1))) unsigned int*)(g), \
    (__attribute__((address_space(3))) unsigned int*)(l), 16, 0, 0)

// ---- bf16 hi/lo split (RTNE) ----
__device__ __forceinline__ void bsplit(float a, ushort& hi, ushort& lo) {
    uint u = __float_as_uint(a);
    uint h = (u + 0x7FFFu + ((u >> 16) & 1u)) >> 16;
    hi = (ushort)h;
    float hf = __uint_as_float(h << 16);
    float r = a - hf;                       // exact (Sterbenz)
    uint u2 = __float_as_uint(r);
    lo = (ushort)((u2 + 0x7FFFu + ((u2 >> 16) & 1u)) >> 16);
}

__device__ __forceinline__ float block_reduce_256(float v, float* sbuf) {
    #pragma unroll
    for (int off = 32; off > 0; off >>= 1) v += __shfl_down(v, off, 64);
    int lane = threadIdx.x & 63, wid = threadIdx.x >> 6;
    if (lane == 0) sbuf[wid] = v;
    __syncthreads();
    float tot = sbuf[0] + sbuf[1] + sbuf[2] + sbuf[3];
    __syncthreads();
    return tot;
}

__device__ __forceinline__ double block_reduce_256d(double v, double* dbuf) {
    #pragma unroll
    for (int off = 32; off > 0; off >>= 1) v += __shfl_down(v, off, 64);
    int lane = threadIdx.x & 63, wid = threadIdx.x >> 6;
    if (lane == 0) dbuf[wid] = v;
    __syncthreads();
    double tot = dbuf[0] + dbuf[1] + dbuf[2] + dbuf[3];
    __syncthreads();
    return tot;
}

// ---- fused conversion: B transpose+split [0,2048) | A split [2048,2176) | mu [2176,2688) ----
__global__ __launch_bounds__(256) void conv_kernel(
    const float* __restrict__ B, const float* __restrict__ A,
    ushort* __restrict__ Bthi, ushort* __restrict__ Btlo,
    ushort* __restrict__ Ahi, ushort* __restrict__ Alo,
    float* __restrict__ mu) {
    __shared__ float s[32][33];
    int b = blockIdx.x, tid = threadIdx.x;
    if (b < 2048) {
        int n0 = (b & 127) * 32, k0 = (b >> 7) * 32;
        int r = tid >> 5, c = tid & 31;
        #pragma unroll
        for (int i = 0; i < 4; ++i)
            s[r + i * 8][c] = B[(size_t)(k0 + r + i * 8) * NDIM + n0 + c];
        __syncthreads();
        int rr = tid >> 4, cc = (tid & 15) * 2;
        #pragma unroll
        for (int i = 0; i < 2; ++i) {
            int n = rr + i * 16;
            float a0 = s[cc][n], a1 = s[cc + 1][n];
            ushort h0, l0, h1, l1;
            bsplit(a0, h0, l0); bsplit(a1, h1, l1);
            size_t o = (size_t)(n0 + n) * KDIM + k0 + cc;
            *(ushort2*)&Bthi[o] = make_ushort2(h0, h1);
            *(ushort2*)&Btlo[o] = make_ushort2(l0, l1);
        }
    } else if (b < 2176) {
        int ab = b - 2048;
        int g = ab * 256 + tid;
        const float4* src = (const float4*)A;
        #pragma unroll
        for (int i = 0; i < 2; ++i) {
            float4 v = src[g * 2 + i];
            ushort4 h, l;
            bsplit(v.x, h.x, l.x); bsplit(v.y, h.y, l.y);
            bsplit(v.z, h.z, l.z); bsplit(v.w, h.w, l.w);
            *(ushort4*)&Ahi[(size_t)g * 8 + i * 4] = h;
            *(ushort4*)&Alo[(size_t)g * 8 + i * 4] = l;
        }
    } else {                                   // mu rows (round-2 passing order)
        int k = b - 2176;
        const float* row = B + (size_t)k * NDIM;
        float ss = 0.f;
        for (int j = tid; j < NDIM; j += 256) ss += row[j];
        float tot = block_reduce_256(ss, &s[0][0]);
        if (tid == 0) mu[k] = tot / (float)NDIM / 10.0f + 0.01f;
    }
}

// ---- T = alpha @ obs via split-bf16 MFMA; global_load_lds staging (unchanged, known-good) ----
__global__ __launch_bounds__(256) void mfma_gemm(
    const ushort* __restrict__ Ahi, const ushort* __restrict__ Alo,
    const ushort* __restrict__ Bthi, const ushort* __restrict__ Btlo,
    float* __restrict__ C) {
    __shared__ __align__(16) ushort Asm[2][GBM * GBK];
    __shared__ __align__(16) ushort Bsm[2][GBN * GBK];
    int tid = threadIdx.x;
    int m0 = blockIdx.y * GBM, n0 = blockIdx.x * GBN;
    int l = tid & 63, w = tid >> 6;
    int wm = w >> 1, wn = w & 1;
    int lr = l & 15, lk = l >> 4;

    f32x4 acc[2][2];
    #pragma unroll
    for (int i = 0; i < 2; ++i)
        #pragma unroll
        for (int j = 0; j < 2; ++j) acc[i][j] = (f32x4){0.f, 0.f, 0.f, 0.f};

    for (int c0 = 0; c0 < KDIM; c0 += GBK) {
        #pragma unroll
        for (int i = 0; i < 4; ++i) {
            int c = tid + i * 256;                   // linear chunk id, lane-consecutive
            int plane = c >> 9, q = c & 511;
            int row = q >> 3, kc = (q & 7) ^ (row & 7);
            const ushort* sa = (plane ? Alo : Ahi) + (size_t)(m0 + row) * KDIM + c0 + kc * 8;
            GLOAD_LDS16(sa, (char*)&Asm[0][0] + c * 16);
            const ushort* sb = (plane ? Btlo : Bthi) + (size_t)(n0 + row) * KDIM + c0 + kc * 8;
            GLOAD_LDS16(sb, (char*)&Bsm[0][0] + c * 16);
        }
        __syncthreads();
        bf16x8 ah[2][2], al[2][2], bh[2][2], bl[2][2];   // [frag][k-slice]
        #pragma unroll
        for (int mf = 0; mf < 2; ++mf)
            #pragma unroll
            for (int s = 0; s < 2; ++s) {
                int ra = wm * 32 + mf * 16 + lr;
                int offa = ra * 128 + (((s * 64) + lk * 16) ^ ((ra & 7) << 4));
                ah[mf][s] = *(const bf16x8*)((const char*)&Asm[0][0] + offa);
                al[mf][s] = *(const bf16x8*)((const char*)&Asm[1][0] + offa);
                int rb = wn * 32 + mf * 16 + lr;
                int offb = rb * 128 + (((s * 64) + lk * 16) ^ ((rb & 7) << 4));
                bh[mf][s] = *(const bf16x8*)((const char*)&Bsm[0][0] + offb);
                bl[mf][s] = *(const bf16x8*)((const char*)&Bsm[1][0] + offb);
            }
        #pragma unroll
        for (int s = 0; s < 2; ++s)
            #pragma unroll
            for (int mf = 0; mf < 2; ++mf)
                #pragma unroll
                for (int nf = 0; nf < 2; ++nf) {
                    acc[mf][nf] = __builtin_amdgcn_mfma_f32_16x16x32_bf16(ah[mf][s], bh[nf][s], acc[mf][nf], 0, 0, 0);
                    acc[mf][nf] = __builtin_amdgcn_mfma_f32_16x16x32_bf16(ah[mf][s], bl[nf][s], acc[mf][nf], 0, 0, 0);
                    acc[mf][nf] = __builtin_amdgcn_mfma_f32_16x16x32_bf16(al[mf][s], bh[nf][s], acc[mf][nf], 0, 0, 0);
                }
        __syncthreads();
    }
    #pragma unroll
    for (int mf = 0; mf < 2; ++mf)
        #pragma unroll
        for (int nf = 0; nf < 2; ++nf)
            #pragma unroll
            for (int j = 0; j < 4; ++j) {
                int rm = m0 + wm * 32 + mf * 16 + lk * 4 + j;
                int cn = n0 + wn * 32 + nf * 16 + lr;
                C[(size_t)rm * NDIM + cn] = acc[mf][nf][j];
            }
}

// ---- segmented fused kernel: 2048 blocks = (k, seg); NO atomic/fence tail ----
__global__ __launch_bounds__(256) void final_kernel(
    const float* __restrict__ T, const float* __restrict__ obs,
    const float* __restrict__ extobs, const float* __restrict__ gamma,
    const float* __restrict__ beta_p, const float* __restrict__ mu,
    float* __restrict__ lams_out, double* __restrict__ partials) {
    __shared__ float Ts[SEG + 16];     // T[k, s*SEG-16 .. s*SEG+SEG)
    __shared__ float Es[SEG + 64];     // E[k, s*SEG-64 .. s*SEG+SEG)
    __shared__ float Os[SEG];
    __shared__ float Gs[MEMD];
    __shared__ float Wt[WTAPS];
    __shared__ double dbuf[4];

    int b = blockIdx.x, tid = threadIdx.x;
    int k = b >> 2, s = b & 3;
    float beta = *beta_p;
    float muk = mu[k];

    const float4* gT = (const float4*)(T + (size_t)k * NDIM);
    const float4* gE = (const float4*)(extobs + (size_t)k * NDIM);
    const float4* gO = (const float4*)(obs + (size_t)k * NDIM);
    float4 z = make_float4(0.f, 0.f, 0.f, 0.f);

    {   // Ts: 260 float4, global idx s*256-4+i (zero for t<0)
        for (int i = tid; i < 260; i += 256) {
            int gi = s * 256 - 4 + i;
            ((float4*)Ts)[i] = (gi >= 0) ? gT[gi] : z;
        }
        // Es: 272 float4, global idx s*256-16+i (zero for t<0)
        for (int i = tid; i < 272; i += 256) {
            int gi = s * 256 - 16 + i;
            ((float4*)Es)[i] = (gi >= 0) ? gE[gi] : z;
        }
        ((float4*)Os)[tid] = gO[s * 256 + tid];
        if (tid < MEMD) Gs[tid] = gamma[(size_t)k * MEMD + tid];
        if (tid >= 64 && tid < 64 + WTAPS) {
            int m = tid - 63;                  // 1..16
            Wt[m - 1] = beta * expf(-beta * (float)m);
        }
    }
    __syncthreads();

    int t_loc = tid * 4;                       // segment-local t
    int t = s * SEG + t_loc;                   // global t
    float win[20];
    float l1[4] = {0.f, 0.f, 0.f, 0.f};
    float l2[4] = {0.f, 0.f, 0.f, 0.f};

    // lam1: 16-tap decay FIR; T[t+j-m] = Ts[t_loc+16+j-m]
    #pragma unroll
    for (int c = 0; c < 5; ++c) *(float4*)&win[c * 4] = *(const float4*)&Ts[t_loc + c * 4];
    #pragma unroll
    for (int m = 1; m <= WTAPS; ++m) {
        float wm = Wt[m - 1];
        #pragma unroll
        for (int j = 0; j < 4; ++j) l1[j] = fmaf(wm, win[16 + j - m], l1[j]);
    }

    // lam2: 64 taps in 4 chunks of 16; E[(t+j)-64+i] = Es[t_loc + i + j]
    #pragma unroll
    for (int c4 = 0; c4 < 4; ++c4) {
        #pragma unroll
        for (int c = 0; c < 5; ++c)
            *(float4*)&win[c * 4] = *(const float4*)&Es[t_loc + c4 * 16 + c * 4];
        #pragma unroll
        for (int i = 0; i < 16; ++i) {
            float g = Gs[c4 * 16 + i];
            #pragma unroll
            for (int j = 0; j < 4; ++j) l2[j] = fmaf(g, win[i + j], l2[j]);
        }
    }
    if (t < MEMD) { l2[0] = 0.f; l2[1] = 0.f; l2[2] = 0.f; l2[3] = 0.f; }

    float4 o = ((const float4*)Os)[tid];
    float oo[4] = {o.x, o.y, o.z, o.w};
    double part = 0.0;
    f32x4 sv;
    #pragma unroll
    for (int j = 0; j < 4; ++j) {
        float x = muk + l1[j] + l2[j];
        float sp = fmaxf(x, 0.f) + log1pf(expf(-fabsf(x)));   // jax softplus
        sv[j] = sp;
        part += (double)(oo[j] * logf(sp) - sp);
    }
    *(f32x4*)&lams_out[(size_t)k * NDIM + t] = sv;

    double dtot = block_reduce_256d(part, dbuf);
    if (tid == 0) partials[b] = dtot;
}

// ---- loglik: deterministic f64 tree over 2048 partials ----
__global__ __launch_bounds__(256) void reduce_kernel(const double* __restrict__ partials,
                                                     float* __restrict__ out) {
    __shared__ double dbuf[4];
    double v = 0.0;
    for (int j = threadIdx.x; j < NPART; j += 256) v += partials[j];
    double tot = block_reduce_256d(v, dbuf);
    if (threadIdx.x == 0) out[0] = (float)tot;
}

extern "C" void kernel_launch(void* const* d_in, const int* in_sizes, int n_in,
                              void* d_out, int out_size, void* d_ws, size_t ws_size,
                              hipStream_t stream) {
    const float* obs    = (const float*)d_in[0];
    const float* extobs = (const float*)d_in[1];
    const float* beta   = (const float*)d_in[2];
    const float* alpha  = (const float*)d_in[3];
    const float* gamma  = (const float*)d_in[4];
    float* out = (float*)d_out;

    char* ws = (char*)d_ws;
    float*  T        = (float*)(ws);                              // 8 MiB
    ushort* Bthi     = (ushort*)(ws + (8u << 20));                // 4 MiB
    ushort* Btlo     = (ushort*)(ws + (12u << 20));               // 4 MiB
    ushort* Ahi      = (ushort*)(ws + (16u << 20));               // 0.5 MiB
    ushort* Alo      = (ushort*)(ws + (16u << 20) + (512u << 10));// 0.5 MiB
    double* partials = (double*)(ws + (17u << 20));               // 16 KiB
    float* mu        = (float*)(ws + (17u << 20) + (32u << 10));  // 2 KiB

    conv_kernel<<<2048 + 128 + 512, 256, 0, stream>>>(obs, alpha, Bthi, Btlo,
                                                      Ahi, Alo, mu);
    mfma_gemm<<<dim3(NDIM / GBN, KDIM / GBM), 256, 0, stream>>>(Ahi, Alo, Bthi, Btlo, T);
    final_kernel<<<NPART, 256, 0, stream>>>(T, obs, extobs, gamma, beta, mu,
                                            out + 1, partials);
    reduce_kernel<<<1, 256, 0, stream>>>(partials, out);
}

// Round 8
// 114.955 us; speedup vs baseline: 1.4037x; 1.0089x over previous
//
#include <hip/hip_runtime.h>
#include <math.h>

#define KDIM 512
#define NDIM 4096
#define MEMD 64
#define WTAPS 16
#define SEG 1024
#define NSEG (NDIM / SEG)          // 4
#define NPART (KDIM * NSEG)        // 2048 partials

#define GBM 64
#define GBN 64
#define GBK 64

typedef short bf16x8 __attribute__((ext_vector_type(8)));
typedef float f32x4 __attribute__((ext_vector_type(4)));

#define GLOAD_LDS16(g, l) __builtin_amdgcn_global_load_lds( \
    (const __attribute__((address_space(1))) unsigned int*)(g), \
    (__attribute__((address_space(3))) unsigned int*)(l), 16, 0, 0)

// ---- bf16 hi/lo split (RTNE) ----
__device__ __forceinline__ void bsplit(float a, ushort& hi, ushort& lo) {
    uint u = __float_as_uint(a);
    uint h = (u + 0x7FFFu + ((u >> 16) & 1u)) >> 16;
    hi = (ushort)h;
    float hf = __uint_as_float(h << 16);
    float r = a - hf;                       // exact (Sterbenz)
    uint u2 = __float_as_uint(r);
    lo = (ushort)((u2 + 0x7FFFu + ((u2 >> 16) & 1u)) >> 16);
}

__device__ __forceinline__ float block_reduce_256(float v, float* sbuf) {
    #pragma unroll
    for (int off = 32; off > 0; off >>= 1) v += __shfl_down(v, off, 64);
    int lane = threadIdx.x & 63, wid = threadIdx.x >> 6;
    if (lane == 0) sbuf[wid] = v;
    __syncthreads();
    float tot = sbuf[0] + sbuf[1] + sbuf[2] + sbuf[3];
    __syncthreads();
    return tot;
}

__device__ __forceinline__ double block_reduce_256d(double v, double* dbuf) {
    #pragma unroll
    for (int off = 32; off > 0; off >>= 1) v += __shfl_down(v, off, 64);
    int lane = threadIdx.x & 63, wid = threadIdx.x >> 6;
    if (lane == 0) dbuf[wid] = v;
    __syncthreads();
    double tot = dbuf[0] + dbuf[1] + dbuf[2] + dbuf[3];
    __syncthreads();
    return tot;
}

// ---- fused conversion: B transpose+split [0,512) | A split [512,640) | mu [640,1152) ----
__global__ __launch_bounds__(256) void conv_kernel(
    const float* __restrict__ B, const float* __restrict__ A,
    ushort* __restrict__ Bthi, ushort* __restrict__ Btlo,
    ushort* __restrict__ Ahi, ushort* __restrict__ Alo,
    float* __restrict__ mu) {
    __shared__ float s[64][65];
    int b = blockIdx.x, tid = threadIdx.x;
    if (b < 512) {                             // 64x64 transpose tile: grid 64(n) x 8(k)
        int n0 = (b & 63) * 64, k0 = (b >> 6) * 64;
        #pragma unroll
        for (int i = 0; i < 4; ++i) {
            int idx = i * 256 + tid;
            int row = idx >> 4, c4 = idx & 15;   // coalesced: 16 float4 per row
            float4 v = *(const float4*)&B[(size_t)(k0 + row) * NDIM + n0 + c4 * 4];
            s[row][c4 * 4 + 0] = v.x; s[row][c4 * 4 + 1] = v.y;
            s[row][c4 * 4 + 2] = v.z; s[row][c4 * 4 + 3] = v.w;
        }
        __syncthreads();
        #pragma unroll
        for (int i = 0; i < 2; ++i) {
            int idx = i * 256 + tid;
            int n = idx >> 3, k8 = idx & 7;      // 8 lanes share n -> 128B store runs
            ushort hs[8], ls[8];
            #pragma unroll
            for (int j = 0; j < 8; ++j) bsplit(s[k8 * 8 + j][n], hs[j], ls[j]);
            size_t o = (size_t)(n0 + n) * KDIM + k0 + k8 * 8;
            *(uint4*)&Bthi[o] = *(const uint4*)hs;
            *(uint4*)&Btlo[o] = *(const uint4*)ls;
        }
    } else if (b < 640) {
        int ab = b - 512;
        int g = ab * 256 + tid;
        const float4* src = (const float4*)A;
        #pragma unroll
        for (int i = 0; i < 2; ++i) {
            float4 v = src[g * 2 + i];
            ushort4 h, l;
            bsplit(v.x, h.x, l.x); bsplit(v.y, h.y, l.y);
            bsplit(v.z, h.z, l.z); bsplit(v.w, h.w, l.w);
            *(ushort4*)&Ahi[(size_t)g * 8 + i * 4] = h;
            *(ushort4*)&Alo[(size_t)g * 8 + i * 4] = l;
        }
    } else {                                   // mu rows (round-2 passing order kept)
        int k = b - 640;
        const float* row = B + (size_t)k * NDIM;
        float ss = 0.f;
        for (int j = tid; j < NDIM; j += 256) ss += row[j];
        float tot = block_reduce_256(ss, &s[0][0]);
        if (tid == 0) mu[k] = tot / (float)NDIM / 10.0f + 0.01f;
    }
}

// ---- T = alpha @ obs via split-bf16 MFMA; double-buffered global_load_lds staging ----
__global__ __launch_bounds__(256) void mfma_gemm(
    const ushort* __restrict__ Ahi, const ushort* __restrict__ Alo,
    const ushort* __restrict__ Bthi, const ushort* __restrict__ Btlo,
    float* __restrict__ C) {
    __shared__ __align__(16) ushort Asm[2][2][GBM * GBK];   // [buf][plane][..]
    __shared__ __align__(16) ushort Bsm[2][2][GBN * GBK];
    int tid = threadIdx.x;
    int m0 = blockIdx.y * GBM, n0 = blockIdx.x * GBN;
    int l = tid & 63, w = tid >> 6;
    int wm = w >> 1, wn = w & 1;
    int lr = l & 15, lk = l >> 4;

    f32x4 acc[2][2];
    #pragma unroll
    for (int i = 0; i < 2; ++i)
        #pragma unroll
        for (int j = 0; j < 2; ++j) acc[i][j] = (f32x4){0.f, 0.f, 0.f, 0.f};

#define STAGE(bb, c0)                                                              \
    _Pragma("unroll")                                                              \
    for (int i_ = 0; i_ < 4; ++i_) {                                               \
        int c_ = tid + i_ * 256;                                                   \
        int plane_ = c_ >> 9, q_ = c_ & 511;                                       \
        int row_ = q_ >> 3, kc_ = (q_ & 7) ^ (row_ & 7);                           \
        const ushort* sa_ = (plane_ ? Alo : Ahi) + (size_t)(m0 + row_) * KDIM + (c0) + kc_ * 8; \
        GLOAD_LDS16(sa_, (char*)&Asm[bb][0][0] + c_ * 16);                         \
        const ushort* sb_ = (plane_ ? Btlo : Bthi) + (size_t)(n0 + row_) * KDIM + (c0) + kc_ * 8; \
        GLOAD_LDS16(sb_, (char*)&Bsm[bb][0][0] + c_ * 16);                         \
    }

    STAGE(0, 0);
    __syncthreads();

    for (int t = 0; t < 8; ++t) {
        int cur = t & 1;
        if (t < 7) { STAGE(cur ^ 1, (t + 1) * GBK); }   // prefetch overlaps MFMA below

        bf16x8 ah[2][2], al[2][2], bh[2][2], bl[2][2];  // [frag][k-slice]
        #pragma unroll
        for (int mf = 0; mf < 2; ++mf)
            #pragma unroll
            for (int s = 0; s < 2; ++s) {
                int ra = wm * 32 + mf * 16 + lr;
                int offa = ra * 128 + (((s * 64) + lk * 16) ^ ((ra & 7) << 4));
                ah[mf][s] = *(const bf16x8*)((const char*)&Asm[cur][0][0] + offa);
                al[mf][s] = *(const bf16x8*)((const char*)&Asm[cur][1][0] + offa);
                int rb = wn * 32 + mf * 16 + lr;
                int offb = rb * 128 + (((s * 64) + lk * 16) ^ ((rb & 7) << 4));
                bh[mf][s] = *(const bf16x8*)((const char*)&Bsm[cur][0][0] + offb);
                bl[mf][s] = *(const bf16x8*)((const char*)&Bsm[cur][1][0] + offb);
            }
        #pragma unroll
        for (int s = 0; s < 2; ++s)
            #pragma unroll
            for (int mf = 0; mf < 2; ++mf)
                #pragma unroll
                for (int nf = 0; nf < 2; ++nf) {
                    acc[mf][nf] = __builtin_amdgcn_mfma_f32_16x16x32_bf16(ah[mf][s], bh[nf][s], acc[mf][nf], 0, 0, 0);
                    acc[mf][nf] = __builtin_amdgcn_mfma_f32_16x16x32_bf16(ah[mf][s], bl[nf][s], acc[mf][nf], 0, 0, 0);
                    acc[mf][nf] = __builtin_amdgcn_mfma_f32_16x16x32_bf16(al[mf][s], bh[nf][s], acc[mf][nf], 0, 0, 0);
                }
        __syncthreads();   // drains prefetch tail (T3-minimal 2-phase) + buffer handoff
    }
#undef STAGE

    #pragma unroll
    for (int mf = 0; mf < 2; ++mf)
        #pragma unroll
        for (int nf = 0; nf < 2; ++nf)
            #pragma unroll
            for (int j = 0; j < 4; ++j) {
                int rm = m0 + wm * 32 + mf * 16 + lk * 4 + j;
                int cn = n0 + wn * 32 + nf * 16 + lr;
                C[(size_t)rm * NDIM + cn] = acc[mf][nf][j];
            }
}

// ---- segmented fused kernel: 2048 blocks = (k, seg); no atomic/fence tail ----
__global__ __launch_bounds__(256) void final_kernel(
    const float* __restrict__ T, const float* __restrict__ obs,
    const float* __restrict__ extobs, const float* __restrict__ gamma,
    const float* __restrict__ beta_p, const float* __restrict__ mu,
    float* __restrict__ lams_out, double* __restrict__ partials) {
    __shared__ float Ts[SEG + 16];     // T[k, s*SEG-16 .. s*SEG+SEG)
    __shared__ float Es[SEG + 64];     // E[k, s*SEG-64 .. s*SEG+SEG)
    __shared__ float Os[SEG];
    __shared__ float Gs[MEMD];
    __shared__ float Wt[WTAPS];
    __shared__ double dbuf[4];

    int b = blockIdx.x, tid = threadIdx.x;
    int k = b >> 2, s = b & 3;
    float beta = *beta_p;
    float muk = mu[k];

    const float4* gT = (const float4*)(T + (size_t)k * NDIM);
    const float4* gE = (const float4*)(extobs + (size_t)k * NDIM);
    const float4* gO = (const float4*)(obs + (size_t)k * NDIM);
    float4 z = make_float4(0.f, 0.f, 0.f, 0.f);

    {   // Ts: 260 float4, global idx s*256-4+i (zero for t<0)
        for (int i = tid; i < 260; i += 256) {
            int gi = s * 256 - 4 + i;
            ((float4*)Ts)[i] = (gi >= 0) ? gT[gi] : z;
        }
        // Es: 272 float4, global idx s*256-16+i (zero for t<0)
        for (int i = tid; i < 272; i += 256) {
            int gi = s * 256 - 16 + i;
            ((float4*)Es)[i] = (gi >= 0) ? gE[gi] : z;
        }
        ((float4*)Os)[tid] = gO[s * 256 + tid];
        if (tid < MEMD) Gs[tid] = gamma[(size_t)k * MEMD + tid];
        if (tid >= 64 && tid < 64 + WTAPS) {
            int m = tid - 63;                  // 1..16
            Wt[m - 1] = beta * expf(-beta * (float)m);
        }
    }
    __syncthreads();

    int t_loc = tid * 4;                       // segment-local t
    int t = s * SEG + t_loc;                   // global t
    float win[20];
    float l1[4] = {0.f, 0.f, 0.f, 0.f};
    float l2[4] = {0.f, 0.f, 0.f, 0.f};

    // lam1: 16-tap decay FIR; T[t+j-m] = Ts[t_loc+16+j-m]
    #pragma unroll
    for (int c = 0; c < 5; ++c) *(float4*)&win[c * 4] = *(const float4*)&Ts[t_loc + c * 4];
    #pragma unroll
    for (int m = 1; m <= WTAPS; ++m) {
        float wm = Wt[m - 1];
        #pragma unroll
        for (int j = 0; j < 4; ++j) l1[j] = fmaf(wm, win[16 + j - m], l1[j]);
    }

    // lam2: 64 taps in 4 chunks of 16; E[(t+j)-64+i] = Es[t_loc + i + j]
    #pragma unroll
    for (int c4 = 0; c4 < 4; ++c4) {
        #pragma unroll
        for (int c = 0; c < 5; ++c)
            *(float4*)&win[c * 4] = *(const float4*)&Es[t_loc + c4 * 16 + c * 4];
        #pragma unroll
        for (int i = 0; i < 16; ++i) {
            float g = Gs[c4 * 16 + i];
            #pragma unroll
            for (int j = 0; j < 4; ++j) l2[j] = fmaf(g, win[i + j], l2[j]);
        }
    }
    if (t < MEMD) { l2[0] = 0.f; l2[1] = 0.f; l2[2] = 0.f; l2[3] = 0.f; }

    float4 o = ((const float4*)Os)[tid];
    float oo[4] = {o.x, o.y, o.z, o.w};
    double part = 0.0;
    f32x4 sv;
    #pragma unroll
    for (int j = 0; j < 4; ++j) {
        float x = muk + l1[j] + l2[j];
        float sp = fmaxf(x, 0.f) + log1pf(expf(-fabsf(x)));   // jax softplus
        sv[j] = sp;
        part += (double)(oo[j] * logf(sp) - sp);
    }
    *(f32x4*)&lams_out[(size_t)k * NDIM + t] = sv;

    double dtot = block_reduce_256d(part, dbuf);
    if (tid == 0) partials[b] = dtot;
}

// ---- loglik: deterministic f64 tree over 2048 partials ----
__global__ __launch_bounds__(256) void reduce_kernel(const double* __restrict__ partials,
                                                     float* __restrict__ out) {
    __shared__ double dbuf[4];
    double v = 0.0;
    for (int j = threadIdx.x; j < NPART; j += 256) v += partials[j];
    double tot = block_reduce_256d(v, dbuf);
    if (threadIdx.x == 0) out[0] = (float)tot;
}

extern "C" void kernel_launch(void* const* d_in, const int* in_sizes, int n_in,
                              void* d_out, int out_size, void* d_ws, size_t ws_size,
                              hipStream_t stream) {
    const float* obs    = (const float*)d_in[0];
    const float* extobs = (const float*)d_in[1];
    const float* beta   = (const float*)d_in[2];
    const float* alpha  = (const float*)d_in[3];
    const float* gamma  = (const float*)d_in[4];
    float* out = (float*)d_out;

    char* ws = (char*)d_ws;
    float*  T        = (float*)(ws);                              // 8 MiB
    ushort* Bthi     = (ushort*)(ws + (8u << 20));                // 4 MiB
    ushort* Btlo     = (ushort*)(ws + (12u << 20));               // 4 MiB
    ushort* Ahi      = (ushort*)(ws + (16u << 20));               // 0.5 MiB
    ushort* Alo      = (ushort*)(ws + (16u << 20) + (512u << 10));// 0.5 MiB
    double* partials = (double*)(ws + (17u << 20));               // 16 KiB
    float* mu        = (float*)(ws + (17u << 20) + (32u << 10));  // 2 KiB

    conv_kernel<<<512 + 128 + 512, 256, 0, stream>>>(obs, alpha, Bthi, Btlo,
                                                     Ahi, Alo, mu);
    mfma_gemm<<<dim3(NDIM / GBN, KDIM / GBM), 256, 0, stream>>>(Ahi, Alo, Bthi, Btlo, T);
    final_kernel<<<NPART, 256, 0, stream>>>(T, obs, extobs, gamma, beta, mu,
                                            out + 1, partials);
    reduce_kernel<<<1, 256, 0, stream>>>(partials, out);
}

// Round 9
// 109.624 us; speedup vs baseline: 1.4719x; 1.0486x over previous
//
#include <hip/hip_runtime.h>
#include <math.h>

#define KDIM 512
#define NDIM 4096
#define MEMD 64
#define WTAPS 16
#define SEG 1024
#define NSEG (NDIM / SEG)          // 4

#define GBM 64
#define GBN 64
#define GBK 64

typedef short bf16x8 __attribute__((ext_vector_type(8)));
typedef float f32x4 __attribute__((ext_vector_type(4)));

#define GLOAD_LDS16(g, l) __builtin_amdgcn_global_load_lds( \
    (const __attribute__((address_space(1))) unsigned int*)(g), \
    (__attribute__((address_space(3))) unsigned int*)(l), 16, 0, 0)

// ---- bf16 hi/lo split (RTNE) ----
__device__ __forceinline__ void bsplit(float a, ushort& hi, ushort& lo) {
    uint u = __float_as_uint(a);
    uint h = (u + 0x7FFFu + ((u >> 16) & 1u)) >> 16;
    hi = (ushort)h;
    float hf = __uint_as_float(h << 16);
    float r = a - hf;                       // exact (Sterbenz)
    uint u2 = __float_as_uint(r);
    lo = (ushort)((u2 + 0x7FFFu + ((u2 >> 16) & 1u)) >> 16);
}

__device__ __forceinline__ float block_reduce_256(float v, float* sbuf) {
    #pragma unroll
    for (int off = 32; off > 0; off >>= 1) v += __shfl_down(v, off, 64);
    int lane = threadIdx.x & 63, wid = threadIdx.x >> 6;
    if (lane == 0) sbuf[wid] = v;
    __syncthreads();
    float tot = sbuf[0] + sbuf[1] + sbuf[2] + sbuf[3];
    __syncthreads();
    return tot;
}

__device__ __forceinline__ double block_reduce_256d(double v, double* dbuf) {
    #pragma unroll
    for (int off = 32; off > 0; off >>= 1) v += __shfl_down(v, off, 64);
    int lane = threadIdx.x & 63, wid = threadIdx.x >> 6;
    if (lane == 0) dbuf[wid] = v;
    __syncthreads();
    double tot = dbuf[0] + dbuf[1] + dbuf[2] + dbuf[3];
    __syncthreads();
    return tot;
}

// ---- fused conversion: B transpose+split [0,512) | A split [512,640) | mu [640,1152) ----
__global__ __launch_bounds__(256) void conv_kernel(
    const float* __restrict__ B, const float* __restrict__ A,
    ushort* __restrict__ Bthi, ushort* __restrict__ Btlo,
    ushort* __restrict__ Ahi, ushort* __restrict__ Alo,
    float* __restrict__ mu) {
    __shared__ float s[64][65];
    int b = blockIdx.x, tid = threadIdx.x;
    if (b < 512) {                             // 64x64 transpose tile
        int n0 = (b & 63) * 64, k0 = (b >> 6) * 64;
        #pragma unroll
        for (int i = 0; i < 4; ++i) {
            int idx = i * 256 + tid;
            int row = idx >> 4, c4 = idx & 15;
            float4 v = *(const float4*)&B[(size_t)(k0 + row) * NDIM + n0 + c4 * 4];
            s[row][c4 * 4 + 0] = v.x; s[row][c4 * 4 + 1] = v.y;
            s[row][c4 * 4 + 2] = v.z; s[row][c4 * 4 + 3] = v.w;
        }
        __syncthreads();
        #pragma unroll
        for (int i = 0; i < 2; ++i) {
            int idx = i * 256 + tid;
            int n = idx >> 3, k8 = idx & 7;
            ushort hs[8], ls[8];
            #pragma unroll
            for (int j = 0; j < 8; ++j) bsplit(s[k8 * 8 + j][n], hs[j], ls[j]);
            size_t o = (size_t)(n0 + n) * KDIM + k0 + k8 * 8;
            *(uint4*)&Bthi[o] = *(const uint4*)hs;
            *(uint4*)&Btlo[o] = *(const uint4*)ls;
        }
    } else if (b < 640) {
        int ab = b - 512;
        int g = ab * 256 + tid;
        const float4* src = (const float4*)A;
        #pragma unroll
        for (int i = 0; i < 2; ++i) {
            float4 v = src[g * 2 + i];
            ushort4 h, l;
            bsplit(v.x, h.x, l.x); bsplit(v.y, h.y, l.y);
            bsplit(v.z, h.z, l.z); bsplit(v.w, h.w, l.w);
            *(ushort4*)&Ahi[(size_t)g * 8 + i * 4] = h;
            *(ushort4*)&Alo[(size_t)g * 8 + i * 4] = l;
        }
    } else {                                   // mu rows (round-2 passing order kept)
        int k = b - 640;
        const float* row = B + (size_t)k * NDIM;
        float ss = 0.f;
        for (int j = tid; j < NDIM; j += 256) ss += row[j];
        float tot = block_reduce_256(ss, &s[0][0]);
        if (tid == 0) mu[k] = tot / (float)NDIM / 10.0f + 0.01f;
    }
}

// ---- T = alpha @ obs via split-bf16 MFMA; double-buffered global_load_lds staging ----
__global__ __launch_bounds__(256) void mfma_gemm(
    const ushort* __restrict__ Ahi, const ushort* __restrict__ Alo,
    const ushort* __restrict__ Bthi, const ushort* __restrict__ Btlo,
    float* __restrict__ C) {
    __shared__ __align__(16) ushort Asm[2][2][GBM * GBK];   // [buf][plane][..]
    __shared__ __align__(16) ushort Bsm[2][2][GBN * GBK];
    int tid = threadIdx.x;
    int m0 = blockIdx.y * GBM, n0 = blockIdx.x * GBN;
    int l = tid & 63, w = tid >> 6;
    int wm = w >> 1, wn = w & 1;
    int lr = l & 15, lk = l >> 4;

    f32x4 acc[2][2];
    #pragma unroll
    for (int i = 0; i < 2; ++i)
        #pragma unroll
        for (int j = 0; j < 2; ++j) acc[i][j] = (f32x4){0.f, 0.f, 0.f, 0.f};

#define STAGE(bb, c0)                                                              \
    _Pragma("unroll")                                                              \
    for (int i_ = 0; i_ < 4; ++i_) {                                               \
        int c_ = tid + i_ * 256;                                                   \
        int plane_ = c_ >> 9, q_ = c_ & 511;                                       \
        int row_ = q_ >> 3, kc_ = (q_ & 7) ^ (row_ & 7);                           \
        const ushort* sa_ = (plane_ ? Alo : Ahi) + (size_t)(m0 + row_) * KDIM + (c0) + kc_ * 8; \
        GLOAD_LDS16(sa_, (char*)&Asm[bb][0][0] + c_ * 16);                         \
        const ushort* sb_ = (plane_ ? Btlo : Bthi) + (size_t)(n0 + row_) * KDIM + (c0) + kc_ * 8; \
        GLOAD_LDS16(sb_, (char*)&Bsm[bb][0][0] + c_ * 16);                         \
    }

    STAGE(0, 0);
    __syncthreads();

    for (int t = 0; t < 8; ++t) {
        int cur = t & 1;
        if (t < 7) { STAGE(cur ^ 1, (t + 1) * GBK); }   // prefetch overlaps MFMA below

        bf16x8 ah[2][2], al[2][2], bh[2][2], bl[2][2];  // [frag][k-slice]
        #pragma unroll
        for (int mf = 0; mf < 2; ++mf)
            #pragma unroll
            for (int s = 0; s < 2; ++s) {
                int ra = wm * 32 + mf * 16 + lr;
                int offa = ra * 128 + (((s * 64) + lk * 16) ^ ((ra & 7) << 4));
                ah[mf][s] = *(const bf16x8*)((const char*)&Asm[cur][0][0] + offa);
                al[mf][s] = *(const bf16x8*)((const char*)&Asm[cur][1][0] + offa);
                int rb = wn * 32 + mf * 16 + lr;
                int offb = rb * 128 + (((s * 64) + lk * 16) ^ ((rb & 7) << 4));
                bh[mf][s] = *(const bf16x8*)((const char*)&Bsm[cur][0][0] + offb);
                bl[mf][s] = *(const bf16x8*)((const char*)&Bsm[cur][1][0] + offb);
            }
        #pragma unroll
        for (int s = 0; s < 2; ++s)
            #pragma unroll
            for (int mf = 0; mf < 2; ++mf)
                #pragma unroll
                for (int nf = 0; nf < 2; ++nf) {
                    acc[mf][nf] = __builtin_amdgcn_mfma_f32_16x16x32_bf16(ah[mf][s], bh[nf][s], acc[mf][nf], 0, 0, 0);
                    acc[mf][nf] = __builtin_amdgcn_mfma_f32_16x16x32_bf16(ah[mf][s], bl[nf][s], acc[mf][nf], 0, 0, 0);
                    acc[mf][nf] = __builtin_amdgcn_mfma_f32_16x16x32_bf16(al[mf][s], bh[nf][s], acc[mf][nf], 0, 0, 0);
                }
        __syncthreads();
    }
#undef STAGE

    #pragma unroll
    for (int mf = 0; mf < 2; ++mf)
        #pragma unroll
        for (int nf = 0; nf < 2; ++nf)
            #pragma unroll
            for (int j = 0; j < 4; ++j) {
                int rm = m0 + wm * 32 + mf * 16 + lk * 4 + j;
                int cn = n0 + wn * 32 + nf * 16 + lr;
                C[(size_t)rm * NDIM + cn] = acc[mf][nf][j];
            }
}

// ---- persistent per-row fused kernel: 512 blocks, 4 segments each,
//      double-buffered LDS + async reg staging (T14): latency paid once ----
__global__ __launch_bounds__(256) void final_kernel(
    const float* __restrict__ T, const float* __restrict__ obs,
    const float* __restrict__ extobs, const float* __restrict__ gamma,
    const float* __restrict__ beta_p, const float* __restrict__ mu,
    float* __restrict__ lams_out, double* __restrict__ partials) {
    __shared__ float Ts[2][SEG + 16];    // T[k, s*SEG-16 .. s*SEG+SEG)
    __shared__ float Es[2][SEG + 64];    // E[k, s*SEG-64 .. s*SEG+SEG)
    __shared__ float Os[2][SEG];
    __shared__ float Gs[MEMD];
    __shared__ float Wt[WTAPS];
    __shared__ double dbuf[4];

    int k = blockIdx.x, tid = threadIdx.x;
    float beta = *beta_p;
    float muk = mu[k];

    const float4* gT = (const float4*)(T + (size_t)k * NDIM);
    const float4* gE = (const float4*)(extobs + (size_t)k * NDIM);
    const float4* gO = (const float4*)(obs + (size_t)k * NDIM);
    float4 z = make_float4(0.f, 0.f, 0.f, 0.f);

    // ---- prologue: stage segment 0 into buffer 0 ----
    for (int i = tid; i < 260; i += 256) {        // Ts: gi = -4 + i
        int gi = i - 4;
        ((float4*)Ts[0])[i] = (gi >= 0) ? gT[gi] : z;
    }
    for (int i = tid; i < 272; i += 256) {        // Es: gi = -16 + i
        int gi = i - 16;
        ((float4*)Es[0])[i] = (gi >= 0) ? gE[gi] : z;
    }
    ((float4*)Os[0])[tid] = gO[tid];
    if (tid < MEMD) Gs[tid] = gamma[(size_t)k * MEMD + tid];
    if (tid >= 64 && tid < 64 + WTAPS) {
        int m = tid - 63;                          // 1..16
        Wt[m - 1] = beta * expf(-beta * (float)m);
    }
    __syncthreads();

    double part = 0.0;
    int t_loc = tid * 4;

    #pragma unroll
    for (int s = 0; s < NSEG; ++s) {
        int cur = s & 1;

        // ---- issue next-segment loads into regs (latency hides under compute) ----
        float4 rT0, rT1, rE0, rE1, rO;
        if (s < NSEG - 1) {
            int base = (s + 1) * 256;
            rT0 = gT[base - 4 + tid];              // gi >= 252, no clamping needed
            if (tid < 4)  rT1 = gT[base + 252 + tid];
            rE0 = gE[base - 16 + tid];
            if (tid < 16) rE1 = gE[base + 240 + tid];
            rO  = gO[base + tid];
        }

        // ---- compute segment s from buffer cur ----
        int t = s * SEG + t_loc;
        float win[20];
        float l1[4] = {0.f, 0.f, 0.f, 0.f};
        float l2[4] = {0.f, 0.f, 0.f, 0.f};

        // lam1: 16-tap decay FIR; T[t+j-m] = Ts[cur][t_loc+16+j-m]
        #pragma unroll
        for (int c = 0; c < 5; ++c)
            *(float4*)&win[c * 4] = *(const float4*)&Ts[cur][t_loc + c * 4];
        #pragma unroll
        for (int m = 1; m <= WTAPS; ++m) {
            float wm = Wt[m - 1];
            #pragma unroll
            for (int j = 0; j < 4; ++j) l1[j] = fmaf(wm, win[16 + j - m], l1[j]);
        }

        // lam2: 64 taps in 4 chunks of 16; E[(t+j)-64+i] = Es[cur][t_loc + i + j]
        #pragma unroll
        for (int c4 = 0; c4 < 4; ++c4) {
            #pragma unroll
            for (int c = 0; c < 5; ++c)
                *(float4*)&win[c * 4] = *(const float4*)&Es[cur][t_loc + c4 * 16 + c * 4];
            #pragma unroll
            for (int i = 0; i < 16; ++i) {
                float g = Gs[c4 * 16 + i];
                #pragma unroll
                for (int j = 0; j < 4; ++j) l2[j] = fmaf(g, win[i + j], l2[j]);
            }
        }
        if (t < MEMD) { l2[0] = 0.f; l2[1] = 0.f; l2[2] = 0.f; l2[3] = 0.f; }

        float4 o = ((const float4*)Os[cur])[tid];
        float oo[4] = {o.x, o.y, o.z, o.w};
        f32x4 sv;
        #pragma unroll
        for (int j = 0; j < 4; ++j) {
            float x = muk + l1[j] + l2[j];
            float sp = fmaxf(x, 0.f) + log1pf(expf(-fabsf(x)));   // jax softplus
            sv[j] = sp;
            part += (double)(oo[j] * logf(sp) - sp);
        }
        *(f32x4*)&lams_out[(size_t)k * NDIM + t] = sv;

        // ---- write prefetched regs into the alternate buffer (no read overlap) ----
        if (s < NSEG - 1) {
            int nxt = cur ^ 1;
            ((float4*)Ts[nxt])[tid] = rT0;
            if (tid < 4)  ((float4*)Ts[nxt])[256 + tid] = rT1;
            ((float4*)Es[nxt])[tid] = rE0;
            if (tid < 16) ((float4*)Es[nxt])[256 + tid] = rE1;
            ((float4*)Os[nxt])[tid] = rO;
            __syncthreads();
        }
    }

    double dtot = block_reduce_256d(part, dbuf);
    if (tid == 0) partials[k] = dtot;
}

// ---- loglik: deterministic f64 tree over 512 partials ----
__global__ __launch_bounds__(256) void reduce_kernel(const double* __restrict__ partials,
                                                     float* __restrict__ out) {
    __shared__ double dbuf[4];
    double v = 0.0;
    for (int j = threadIdx.x; j < KDIM; j += 256) v += partials[j];
    double tot = block_reduce_256d(v, dbuf);
    if (threadIdx.x == 0) out[0] = (float)tot;
}

extern "C" void kernel_launch(void* const* d_in, const int* in_sizes, int n_in,
                              void* d_out, int out_size, void* d_ws, size_t ws_size,
                              hipStream_t stream) {
    const float* obs    = (const float*)d_in[0];
    const float* extobs = (const float*)d_in[1];
    const float* beta   = (const float*)d_in[2];
    const float* alpha  = (const float*)d_in[3];
    const float* gamma  = (const float*)d_in[4];
    float* out = (float*)d_out;

    char* ws = (char*)d_ws;
    float*  T        = (float*)(ws);                              // 8 MiB
    ushort* Bthi     = (ushort*)(ws + (8u << 20));                // 4 MiB
    ushort* Btlo     = (ushort*)(ws + (12u << 20));               // 4 MiB
    ushort* Ahi      = (ushort*)(ws + (16u << 20));               // 0.5 MiB
    ushort* Alo      = (ushort*)(ws + (16u << 20) + (512u << 10));// 0.5 MiB
    double* partials = (double*)(ws + (17u << 20));               // 4 KiB
    float* mu        = (float*)(ws + (17u << 20) + (32u << 10));  // 2 KiB

    conv_kernel<<<512 + 128 + 512, 256, 0, stream>>>(obs, alpha, Bthi, Btlo,
                                                     Ahi, Alo, mu);
    mfma_gemm<<<dim3(NDIM / GBN, KDIM / GBM), 256, 0, stream>>>(Ahi, Alo, Bthi, Btlo, T);
    final_kernel<<<KDIM, 256, 0, stream>>>(T, obs, extobs, gamma, beta, mu,
                                           out + 1, partials);
    reduce_kernel<<<1, 256, 0, stream>>>(partials, out);
}